// Round 9
// baseline (350.923 us; speedup 1.0000x reference)
//
#include <hip/hip_runtime.h>

#define TT   256
#define HID  30
#define LOG2E 1.4426950408889634f
#define HS   56        // h-row stride in bf16 (112B: 2-way banks only, free)
#define XW   772       // x row stride in f32 in LDS

typedef __bf16 bf16x8_t __attribute__((ext_vector_type(8)));
typedef float  f32x4_t  __attribute__((ext_vector_type(4)));

__device__ __forceinline__ float fexp2(float x){
#if __has_builtin(__builtin_amdgcn_exp2f)
    return __builtin_amdgcn_exp2f(x);
#else
    return exp2f(x);
#endif
}
__device__ __forceinline__ float frcp(float x){
#if __has_builtin(__builtin_amdgcn_rcpf)
    return __builtin_amdgcn_rcpf(x);
#else
    return 1.f/x;
#endif
}
__device__ __forceinline__ float fsigmoid(float x){ return frcp(1.f + fexp2(-LOG2E*x)); }
__device__ __forceinline__ f32x4_t exp4(f32x4_t v){
    f32x4_t e; e[0]=fexp2(v[0]); e[1]=fexp2(v[1]); e[2]=fexp2(v[2]); e[3]=fexp2(v[3]); return e;
}
__device__ __forceinline__ f32x4_t rcp4(f32x4_t v){
    f32x4_t r; r[0]=frcp(v[0]); r[1]=frcp(v[1]); r[2]=frcp(v[2]); r[3]=frcp(v[3]); return r;
}
__device__ __forceinline__ f32x4_t sig4(f32x4_t v){ return rcp4(exp4(v*(-LOG2E)) + 1.f); }
__device__ __forceinline__ f32x4_t tanh4(f32x4_t v){ return rcp4(exp4(v*(-2.f*LOG2E)) + 1.f)*2.f - 1.f; }

#define MFMA(A,B,C) __builtin_amdgcn_mfma_f32_16x16x32_bf16(A,B,C,0,0,0)

// K=4-deep skewed producer/consumer. Wave0 (layer0) runs a full 4-step
// super-iteration AHEAD of wave1 (layer1); h0 flows through a triple-buffered
// ring h0r[3][4] so wave1 only ever reads data written >=1 super (~5000 cyc)
// ago. ONE barrier per 4 steps (vs 1/step in R4-R8) -- removes the per-step
// write->barrier->read serial handoff that pinned wall at ~2550 cyc/step.
// Gate-major lane-local tiling from R7/R8 (no shfl); x fully LDS-resident.
__global__ __launch_bounds__(128)
void lstm_fused(const float* __restrict__ x,
    const float* __restrict__ Wih0, const float* __restrict__ Whh0,
    const float* __restrict__ bih0, const float* __restrict__ bhh0,
    const float* __restrict__ Wih1, const float* __restrict__ Whh1,
    const float* __restrict__ bih1, const float* __restrict__ bhh1,
    const float* __restrict__ Wfc1, const float* __restrict__ bfc1,
    const float* __restrict__ Wfc2, const float* __restrict__ bfc2,
    const float* __restrict__ Wfc3, const float* __restrict__ bfc3,
    float* __restrict__ out)
{
    __shared__ __align__(16) float  sx[16*XW];          // x slice (reused as FC scratch)
    __shared__ __align__(16) __bf16 h0r[3][4][16][HS];  // h0 ring: [buf][slot][m][k]; k30,31=x0,x1(t+1)
    __shared__ __align__(16) __bf16 h1f[16][HS];        // wave-1-private h1 (single buf)
    __shared__ float h1_last[16*32];

    const int tid  = threadIdx.x;
    const int lane = tid & 63;
    const int wv   = tid >> 6;       // 0 = layer-0 producer, 1 = layer-1 consumer
    const int n    = lane & 15;
    const int q    = lane >> 4;
    const int bbase = blockIdx.x * 16;

    // ---- stage x (16 rows x 768 f32 = 48 KB) into LDS once ----
    {
        const float* xB = x + (size_t)bbase * 768;
        #pragma unroll
        for (int it = 0; it < 24; ++it) {
            int flat = (it*128 + tid) * 4;
            int m = flat / 768;
            int o = flat - m*768;
            *(float4*)(&sx[m*XW + o]) = *(const float4*)(xB + (size_t)m*768 + o);
        }
    }

    // ---- resident B-fragments, gate-major tiling (R7/R8 layout) ----
    // tile t: gate G=t>>1 (i,f,g,o), units u=(t&1)*16+n (valid u<30)
    // wave0: fbA = Whh0 (+Wih0 cols0,1 at k30/31); wave1: fbA = Wih1, fbB = Whh1
    bf16x8_t fbA[8], fbB[8];
    float bias[8], wx2v[8];
    #pragma unroll
    for (int t = 0; t < 8; ++t) {
        const int G = t >> 1;
        const int u = (t & 1)*16 + n;
        const bool ok = (u < HID);
        const int row = G*HID + (ok ? u : 0);
        #pragma unroll
        for (int j = 0; j < 8; ++j) {
            const int k = q*8 + j;
            float vA = 0.f, vB = 0.f;
            if (ok) {
                if (wv == 0) {
                    vA = (k < HID) ? Whh0[row*HID + k] : Wih0[row*3 + (k - HID)];
                } else if (k < HID) {
                    vA = Wih1[row*HID + k];
                    vB = Whh1[row*HID + k];
                }
            }
            fbA[t][j] = (__bf16)vA;
            fbB[t][j] = (__bf16)vB;
        }
        bias[t] = ok ? (wv == 0 ? bih0[row] + bhh0[row] : bih1[row] + bhh1[row]) : 0.f;
        wx2v[t] = (ok && wv == 0) ? Wih0[row*3 + 2] : 0.f;
    }

    f32x4_t cA = {0.f,0.f,0.f,0.f};   // c state, units n
    f32x4_t cB = {0.f,0.f,0.f,0.f};   // c state, units 16+n

    for (int i = tid; i < 3*4*16*HS; i += 128) (&h0r[0][0][0][0])[i] = (__bf16)0.f;
    for (int i = tid; i < 16*HS;     i += 128) (&h1f[0][0])[i]       = (__bf16)0.f;
    __syncthreads();   // staging + zero-init visible to both waves

#define ACTS(d)                                                              \
    f32x4_t i0 = sig4(d[0]),  i1 = sig4(d[1]);                               \
    f32x4_t f0 = sig4(d[2]),  f1 = sig4(d[3]);                               \
    f32x4_t g0 = tanh4(d[4]), g1 = tanh4(d[5]);                              \
    f32x4_t o0 = sig4(d[6]),  o1 = sig4(d[7]);                               \
    cA = f0*cA + i0*g0;                                                      \
    cB = f1*cB + i1*g1;                                                      \
    f32x4_t hA = o0*tanh4(cA);                                               \
    f32x4_t hB = o1*tanh4(cB);

// wave0: produce h0(T) reading ring slot (PR,JR), writing (PW,JW) (+x01(T+1))
#define W0STEP(T, PR, JR, PW, JW) do {                                       \
    bf16x8_t A0 = *(const bf16x8_t*)((PR) + ((JR)*16 + n)*HS + q*8);         \
    f32x4_t x2;                                                              \
    _Pragma("unroll")                                                        \
    for (int r = 0; r < 4; ++r) x2[r] = sx[(q*4+r)*XW + (T)*3 + 2];          \
    f32x4_t d[8];                                                            \
    _Pragma("unroll")                                                        \
    for (int t = 0; t < 8; ++t) d[t] = MFMA(A0, fbA[t], x2*wx2v[t]+bias[t]); \
    ACTS(d)                                                                  \
    __bf16* wp = (PW) + (JW)*16*HS;                                          \
    _Pragma("unroll")                                                        \
    for (int r = 0; r < 4; ++r) wp[(q*4+r)*HS + n] = (__bf16)hA[r];          \
    if (n < 14) {                                                            \
        _Pragma("unroll")                                                    \
        for (int r = 0; r < 4; ++r) wp[(q*4+r)*HS + 16+n] = (__bf16)hB[r];   \
    }                                                                        \
    { int Tc = (T) + 1; if (Tc > TT-1) Tc = TT-1;                            \
      if (lane < 32)                                                         \
        wp[(lane>>1)*HS + 30 + (lane&1)] =                                   \
            (__bf16)sx[(lane>>1)*XW + Tc*3 + (lane&1)]; }                    \
} while (0)

// wave1: produce h1(T) reading h0 ring slot (PR,JR) + private h1f
#define W1STEP(T, PR, JR) do {                                               \
    bf16x8_t A1 = *(const bf16x8_t*)((PR) + ((JR)*16 + n)*HS + q*8);         \
    bf16x8_t A2 = *(const bf16x8_t*)(&h1f[n][q*8]);                          \
    f32x4_t d[8];                                                            \
    _Pragma("unroll")                                                        \
    for (int t = 0; t < 8; ++t) {                                            \
        f32x4_t e = {bias[t], bias[t], bias[t], bias[t]};                    \
        d[t] = MFMA(A1, fbA[t], e);                                          \
    }                                                                        \
    _Pragma("unroll")                                                        \
    for (int t = 0; t < 8; ++t) d[t] = MFMA(A2, fbB[t], d[t]);               \
    ACTS(d)                                                                  \
    _Pragma("unroll")                                                        \
    for (int r = 0; r < 4; ++r) h1f[q*4+r][n] = (__bf16)hA[r];               \
    if (n < 14) {                                                            \
        _Pragma("unroll")                                                    \
        for (int r = 0; r < 4; ++r) h1f[q*4+r][16+n] = (__bf16)hB[r];        \
    }                                                                        \
    if ((T) == TT-1) {                                                       \
        _Pragma("unroll")                                                    \
        for (int r = 0; r < 4; ++r) {                                        \
            h1_last[(q*4+r)*32 + n] = hA[r];                                 \
            if (n < 14) h1_last[(q*4+r)*32 + 16+n] = hB[r];                  \
        }                                                                    \
    }                                                                        \
} while (0)

    // ---- prologue: wave0 builds h0(0) from zeros + x01(0) (slot [2][2] -> [2][3]) ----
    if (wv == 0) {
        if (lane < 32)
            h0r[2][2][lane>>1][30+(lane&1)] = (__bf16)sx[(lane>>1)*XW + (lane&1)];
        __bf16* b2 = &h0r[2][0][0][0];
        W0STEP(0, b2, 2, b2, 3);
    }
    __syncthreads();

    // ---- supers: wave0 produces h0(4k+1..4k+4) into buf k%3;
    //      wave1 consumes buf (k-1)%3 -> h1(4k-3..4k). One barrier per super. ----
    int kw = 0;   // k % 3
    #pragma unroll 1
    for (int k = 0; k < 64; ++k) {
        __bf16* bW = &h0r[kw][0][0][0];
        const int kr = (kw == 0) ? 2 : kw - 1;
        const __bf16* bR = &h0r[kr][0][0][0];
        if (wv == 0) {
            if (k < 63) {
                const int T = 4*k;
                W0STEP(T+1, bR, 3, bW, 0);
                W0STEP(T+2, bW, 0, bW, 1);
                W0STEP(T+3, bW, 1, bW, 2);
                W0STEP(T+4, bW, 2, bW, 3);
            } else {            // k=63: produce h0(253..255) only
                W0STEP(253, bR, 3, bW, 0);
                W0STEP(254, bW, 0, bW, 1);
                W0STEP(255, bW, 1, bW, 2);
            }
        } else {
            if (k == 0) {
                W1STEP(0, bR, 3);      // h1(0) from prologue's h0(0)
            } else {
                const int t0 = 4*k - 3;
                W1STEP(t0,   bR, 0);
                W1STEP(t0+1, bR, 1);
                W1STEP(t0+2, bR, 2);
                W1STEP(t0+3, bR, 3);
            }
        }
        __syncthreads();
        kw = (kw == 2) ? 0 : kw + 1;
    }
    // epilogue: wave1 consumes buf 0 (written at k=63) -> h1(253..255)
    if (wv == 1) {
        const __bf16* bR = &h0r[0][0][0][0];
        W1STEP(253, bR, 0);
        W1STEP(254, bR, 1);
        W1STEP(255, bR, 2);
    }
    __syncthreads();

#undef W0STEP
#undef W1STEP
#undef ACTS

    // ---- FC head (128 threads; scratch aliases sx, which is now dead) ----
    #pragma unroll
    for (int rep = 0; rep < 8; ++rep) {
        int idx = tid + rep*128;          // 16*64 outputs
        int m = idx >> 6, uu = idx & 63;
        float a = bfc1[uu];
        for (int kk = 0; kk < HID; ++kk) a += h1_last[m*32+kk] * Wfc1[uu*HID+kk];
        sx[m*64+uu] = fmaxf(a, 0.f);      // zbuf = sx[0..1023]
    }
    __syncthreads();
    #pragma unroll
    for (int rep = 0; rep < 4; ++rep) {
        int idx = tid + rep*128;          // 16*32 outputs
        int m = idx >> 5, v = idx & 31;
        float a = bfc2[v];
        for (int kk = 0; kk < 64; ++kk) a += sx[m*64+kk] * Wfc2[v*64+kk];
        sx[1024 + m*32+v] = fmaxf(a, 0.f); // z2buf = sx[1024..1535]
    }
    __syncthreads();
    if (tid < 16) {
        float a = bfc3[0];
        for (int kk = 0; kk < 32; ++kk) a += sx[1024 + tid*32+kk] * Wfc3[kk];
        out[bbase + tid] = fsigmoid(a);
    }
}

extern "C" void kernel_launch(void* const* d_in, const int* in_sizes, int n_in,
                              void* d_out, int out_size, void* d_ws, size_t ws_size,
                              hipStream_t stream) {
    const float* x    = (const float*)d_in[0];
    const float* Wih0 = (const float*)d_in[1];
    const float* Whh0 = (const float*)d_in[2];
    const float* bih0 = (const float*)d_in[3];
    const float* bhh0 = (const float*)d_in[4];
    const float* Wih1 = (const float*)d_in[5];
    const float* Whh1 = (const float*)d_in[6];
    const float* bih1 = (const float*)d_in[7];
    const float* bhh1 = (const float*)d_in[8];
    const float* Wfc1 = (const float*)d_in[9];
    const float* bfc1 = (const float*)d_in[10];
    const float* Wfc2 = (const float*)d_in[11];
    const float* bfc2 = (const float*)d_in[12];
    const float* Wfc3 = (const float*)d_in[13];
    const float* bfc3 = (const float*)d_in[14];
    float* outp = (float*)d_out;

    hipLaunchKernelGGL(lstm_fused, dim3(512), dim3(128), 0, stream,
        x, Wih0, Whh0, bih0, bhh0, Wih1, Whh1, bih1, bhh1,
        Wfc1, bfc1, Wfc2, bfc2, Wfc3, bfc3, outp);
}